// Round 7
// baseline (103.374 us; speedup 1.0000x reference)
//
#include <hip/hip_runtime.h>
#include <hip/hip_bf16.h>

// Problem constants: B=64, Cin=3, H=W=64, O=16, k=7, fh=fw=58
#define O_ 16
#define CIN 3
#define NBUCK 512
#define WB 0.0009765625f       // bucket width = 1/1024, range [-0.25, 0.25)
#define NCLASS 169             // 13 row-classes x 13 col-classes
#define CL_INT 84              // interior class (rc=6, cc=6)

// output geometry
#define SEG 10092u             // fh*fh*Cin
#define OSEG 161472u           // O*SEG
#define OUT1 10334208u         // B*OSEG
#define NOUT 31002624u         // 3*OUT1

// scratch in the TAIL of d_out (fill overwrites last). float offsets:
#define TAIL_BASE (NOUT - 786432u)      // 30,216,192
#define T_PART  0u                       // 192 slots x 1360: [0..512) int-hist, [512..1357) scalars 169x5
#define T_BHIST 261120u                  // 3*169*512 count hist (atomics for boundary classes)
#define T_SCAL  520704u                  // 3*169*5 reduced scalars
#define T_TTAB  523240u                  // 3*169*513 T tables

#define BHIST_FLOATS 259584u             // 3*169*512
#define BHIST_V4 64896u

typedef float v4f __attribute__((ext_vector_type(4)));

// ---------------------------------------------------------------------------
// 0) zero: parallel zero of the boundary-class histogram region + gsum.
//    (hipMemsetAsync of ~1MB graph-captures as a near-serial rocclr fill
//     kernel that cost 71us/replay in R5 -- this replaces it at ~1-2us.)
// ---------------------------------------------------------------------------
__global__ __launch_bounds__(256) void zero_kernel(
    float* __restrict__ tail, float* __restrict__ gsum)
{
    v4f z = {0.f, 0.f, 0.f, 0.f};
    v4f* dst = (v4f*)(tail + T_BHIST);
    unsigned stride = gridDim.x * blockDim.x;
    for (unsigned i = blockIdx.x * blockDim.x + threadIdx.x; i < BHIST_V4; i += stride)
        dst[i] = z;
    if (blockIdx.x == 0 && threadIdx.x < 32) gsum[threadIdx.x] = 0.f;
}

// ---------------------------------------------------------------------------
// 1) build: one block per (b,c) plane. LDS: interior in-range count hist +
//    per-class scalars (cntL,sumL,cntR,sumR,sumIn). Boundary in-range counts
//    go straight to global atomics (spread over 258K addresses -> ~0 contention).
//    Interior hist + scalars -> private per-plane slot (plain stores).
// ---------------------------------------------------------------------------
__global__ __launch_bounds__(256) void build_kernel(
    const float* __restrict__ x, float* __restrict__ tail)
{
    __shared__ float sH[NBUCK];
    __shared__ float sS[NCLASS * 5];
    for (int i = threadIdx.x; i < NBUCK; i += 256) sH[i] = 0.f;
    for (int i = threadIdx.x; i < NCLASS * 5; i += 256) sS[i] = 0.f;
    __syncthreads();

    const int plane = blockIdx.x;
    const int c     = plane % 3;
    const float4* src = (const float4*)(x + plane * 4096);
    float* bhist = tail + T_BHIST + (unsigned)c * (NCLASS * NBUCK);

#pragma unroll
    for (int it = 0; it < 4; ++it) {
        int f4 = it * 256 + threadIdx.x;
        float4 val = src[f4];
        float vv[4] = {val.x, val.y, val.z, val.w};
        int pix0 = f4 * 4;
#pragma unroll
        for (int e = 0; e < 4; ++e) {
            int idx = pix0 + e;
            int py = idx >> 6, px = idx & 63;
            int rc = (py < 6) ? py : ((py >= 58) ? py - 51 : 6);
            int cc = (px < 6) ? px : ((px >= 58) ? px - 51 : 6);
            int cl = rc * 13 + cc;
            float v = vv[e];
            if (v < -0.25f) {
                atomicAdd(&sS[cl * 5 + 0], 1.f);
                atomicAdd(&sS[cl * 5 + 1], v);
            } else if (v >= 0.25f) {
                atomicAdd(&sS[cl * 5 + 2], 1.f);
                atomicAdd(&sS[cl * 5 + 3], v);
            } else {
                atomicAdd(&sS[cl * 5 + 4], v);
                int b = (int)((v + 0.25f) * 1024.f);
                b = min(max(b, 0), NBUCK - 1);
                if (cl == CL_INT) atomicAdd(&sH[b], 1.f);
                else              atomicAdd(&bhist[cl * NBUCK + b], 1.f);
            }
        }
    }
    __syncthreads();
    float* part = tail + T_PART + (unsigned)plane * 1360u;
    for (int i = threadIdx.x; i < NBUCK; i += 256) part[i] = sH[i];
    for (int i = threadIdx.x; i < NCLASS * 5; i += 256) part[NBUCK + i] = sS[i];
}

// ---------------------------------------------------------------------------
// 2) reduce: fold 64 plane-slots per channel into interior hist + scalars.
// ---------------------------------------------------------------------------
__global__ __launch_bounds__(256) void reduce_kernel(float* __restrict__ tail)
{
    int tid = blockIdx.x * 256 + threadIdx.x;
    if (tid < 3 * NBUCK) {
        int c = tid / NBUCK, b = tid % NBUCK;
        float s = 0.f;
        for (int i = 0; i < 64; ++i)
            s += tail[T_PART + (unsigned)(3 * i + c) * 1360u + b];
        tail[T_BHIST + ((unsigned)c * NCLASS + CL_INT) * NBUCK + b] = s;
    } else if (tid < 3 * NBUCK + 3 * NCLASS * 5) {
        int j = tid - 3 * NBUCK;
        int c = j / (NCLASS * 5), r = j % (NCLASS * 5);
        float s = 0.f;
        for (int i = 0; i < 64; ++i)
            s += tail[T_PART + (unsigned)(3 * i + c) * 1360u + NBUCK + r];
        tail[T_SCAL + (unsigned)c * (NCLASS * 5) + r] = s;
    }
}

// ---------------------------------------------------------------------------
// 3) tbuild: per (c,class) wave: T[j] = sum_b cnt_b * |center_j - center_b|
//    via double prefix scan:  T[j] = T0 + w*(2*Q[j] - j*N),  Q[j]=sum_{i<j}P[i].
// ---------------------------------------------------------------------------
__global__ __launch_bounds__(64) void tbuild_kernel(float* __restrict__ tail)
{
    __shared__ float P[NBUCK];
    const int id = blockIdx.x;                   // c*169+cl
    const float* hist = tail + T_BHIST + (unsigned)id * NBUCK;
    float* T = tail + T_TTAB + (unsigned)id * 513u;
    const int lane = threadIdx.x;

    float carry = 0.f, t0acc = 0.f;
#pragma unroll
    for (int ch = 0; ch < 8; ++ch) {
        int b = ch * 64 + lane;
        float cnt = hist[b];
        t0acc += (float)b * cnt;
        float ic = cnt;
#pragma unroll
        for (int off = 1; off < 64; off <<= 1) {
            float tc = __shfl_up(ic, off);
            if (lane >= off) ic += tc;
        }
        P[b] = carry + ic;
        carry += __shfl(ic, 63);
    }
    const float N = carry;                       // total in-range count
#pragma unroll
    for (int off = 32; off > 0; off >>= 1) t0acc += __shfl_down(t0acc, off);
    const float T0 = WB * __shfl(t0acc, 0);
    __syncthreads();

    float carryQ = 0.f;
#pragma unroll
    for (int ch = 0; ch < 8; ++ch) {
        int b = ch * 64 + lane;
        float pv = P[b];
        float ic = pv;
#pragma unroll
        for (int off = 1; off < 64; off <<= 1) {
            float tc = __shfl_up(ic, off);
            if (lane >= off) ic += tc;
        }
        float Q = carryQ + ic - pv;              // exclusive
        T[b] = T0 + WB * (2.f * Q - (float)b * N);
        carryQ += __shfl(ic, 63);
    }
    if (lane == 0) T[512] = T0 + WB * (2.f * carryQ - 512.f * N);
}

// ---------------------------------------------------------------------------
// 4) query: 4704 threads, one per (hm,o,c,dy,dx). Per valid class:
//    abs  += lerp(T,k) + (k*cntL - sumL) + (sumR - k*cntR)
//    lin  += k*Ntot_cl - (sumL + sumR + sumIn)
//    hit:  sum relu(k-v) = 0.5*(lin+abs);  miss: sum relu(v-k) = 0.5*(abs-lin)
// ---------------------------------------------------------------------------
__global__ __launch_bounds__(256) void query_kernel(
    const float* __restrict__ Kh, const float* __restrict__ Km,
    const float* __restrict__ tail, float* __restrict__ gsum)
{
    int tid = blockIdx.x * 256 + threadIdx.x;
    if (tid >= 4704) return;
    int hm = tid / 2352; int r = tid - hm * 2352;
    int o = r / 147;     int r2 = r - o * 147;
    int c = r2 / 49;     int t = r2 - c * 49;
    int dy = t / 7,      dx = t - dy * 7;
    float k = (hm ? Km : Kh)[(o * 3 + c) * 49 + t];
    float fb = (k + 0.25f) * 1024.f;
    int j = min(max((int)fb, 0), NBUCK - 1);
    float frac = fb - (float)j;

    float accA = 0.f, accL = 0.f;
    for (int i = 0; i < 7; ++i) {
        int rc = dy + i;
        float nr = (rc == 6) ? 52.f : 1.f;
        for (int jj = 0; jj < 7; ++jj) {
            int cc = dx + jj;
            float nc = (cc == 6) ? 52.f : 1.f;
            int id = c * NCLASS + rc * 13 + cc;
            const float* T  = tail + T_TTAB + (unsigned)id * 513u;
            const float* S5 = tail + T_SCAL + (unsigned)id * 5u;
            float t0 = T[j], t1 = T[j + 1];
            float A = t0 + frac * (t1 - t0);
            float cntL = S5[0], sumL = S5[1], cntR = S5[2], sumR = S5[3], sumIn = S5[4];
            accA += A + (k * cntL - sumL) + (sumR - k * cntR);
            accL += k * (nr * nc * 64.f) - (sumL + sumR + sumIn);
        }
    }
    if (hm == 0) atomicAdd(&gsum[o],      0.5f * (accL + accA));
    else         atomicAdd(&gsum[16 + o], 0.5f * (accA - accL));
}

// ---------------------------------------------------------------------------
// 5) fill: s_hit = -gsum[o], s_miss = gsum[16+o]; broadcast-fill 124 MB.
// ---------------------------------------------------------------------------
__global__ __launch_bounds__(256) void fill_kernel(
    const float* __restrict__ gsum, v4f* __restrict__ out, unsigned n4)
{
    __shared__ float sv[48];
    if (threadIdx.x < 48) {
        int o = threadIdx.x & 15, grp = threadIdx.x >> 4;
        float h = -gsum[o];
        float m = gsum[16 + o];
        sv[threadIdx.x] = (grp == 0) ? (h - m) : ((grp == 1) ? h : m);
    }
    __syncthreads();
    unsigned stride = gridDim.x * blockDim.x;
    for (unsigned i = blockIdx.x * blockDim.x + threadIdx.x; i < n4; i += stride) {
        unsigned f = i * 4u;
        unsigned w   = f / OUT1;
        unsigned rem = f - w * OUT1;
        unsigned o   = (rem % OSEG) / SEG;
        float val = sv[w * 16 + o];
        v4f pk = {val, val, val, val};
        __builtin_nontemporal_store(pk, &out[i]);
    }
}

extern "C" void kernel_launch(void* const* d_in, const int* in_sizes, int n_in,
                              void* d_out, int out_size, void* d_ws, size_t ws_size,
                              hipStream_t stream)
{
    const float* x  = (const float*)d_in[0];
    const float* Kh = (const float*)d_in[1];
    const float* Km = (const float*)d_in[2];
    float* out  = (float*)d_out;
    float* tail = out + TAIL_BASE;
    float* gsum = (float*)d_ws;        // 32 floats

    zero_kernel  <<<512, 256, 0, stream>>>(tail, gsum);
    build_kernel <<<192, 256, 0, stream>>>(x, tail);
    reduce_kernel<<<16, 256, 0, stream>>>(tail);
    tbuild_kernel<<<507, 64, 0, stream>>>(tail);
    query_kernel <<<19, 256, 0, stream>>>(Kh, Km, tail, gsum);
    fill_kernel  <<<4096, 256, 0, stream>>>(gsum, (v4f*)out, NOUT / 4u);
}

// Round 8
// 92.563 us; speedup vs baseline: 1.1168x; 1.1168x over previous
//
#include <hip/hip_runtime.h>
#include <hip/hip_bf16.h>

// Problem constants: B=64, Cin=3, H=W=64, O=16, k=7, fh=fw=58
#define O_ 16
#define CIN 3
#define NBUCK 512
#define WB 0.0009765625f       // bucket width = 1/1024, range [-0.25, 0.25)
#define NCLASS 169             // 13 row-classes x 13 col-classes
#define CL_INT 84              // interior class (rc=6, cc=6)

// output geometry
#define SEG 10092u             // fh*fh*Cin
#define OSEG 161472u           // O*SEG
#define OUT1 10334208u         // B*OSEG
#define NOUT 31002624u         // 3*OUT1

// scratch in the TAIL of d_out (fill overwrites last). float offsets:
#define TAIL_BASE (NOUT - 786432u)      // 30,216,192
#define T_BHIST 0u                       // 3*169*512 = 259,584 count hist (ALL classes, atomics)
#define T_SCAL  259584u                  // 3*169*5 = 2,535 scalars (atomics)
#define T_TTAB  262144u                  // 3*169*513 T tables
#define ZERO_V4 65536u                   // zero [0, 262144) floats = hist + scalars

typedef float v4f __attribute__((ext_vector_type(4)));

// ---------------------------------------------------------------------------
// 0) zero: parallel zero of hist+scalar region + gsum (~1 MB, ~2 us).
// ---------------------------------------------------------------------------
__global__ __launch_bounds__(256) void zero_kernel(
    float* __restrict__ tail, float* __restrict__ gsum)
{
    v4f z = {0.f, 0.f, 0.f, 0.f};
    v4f* dst = (v4f*)tail;
    unsigned stride = gridDim.x * blockDim.x;
    for (unsigned i = blockIdx.x * blockDim.x + threadIdx.x; i < ZERO_V4; i += stride)
        dst[i] = z;
    if (blockIdx.x == 0 && threadIdx.x < 32) gsum[threadIdx.x] = 0.f;
}

// ---------------------------------------------------------------------------
// 1) build: one block per (b,c) plane.
//    Interior class (2704/4096 pixels): scalars in REGISTERS (no same-address
//    LDS atomic hammering -- that serialization was R6's hidden ~30us), wave
//    shuffle-reduce, 5 global atomics/block. Interior in-range hist: LDS
//    (spread over 512 buckets), flushed with spread global atomicAdds.
//    Boundary classes: LDS atomics (<=52 deep), flushed likewise.
// ---------------------------------------------------------------------------
__global__ __launch_bounds__(256) void build_kernel(
    const float* __restrict__ x, float* __restrict__ tail)
{
    __shared__ float sH[NBUCK];          // interior in-range count hist
    __shared__ float sS[NCLASS * 5];     // boundary-class scalars (CL_INT slots unused)
    __shared__ float sred[4][5];
    for (int i = threadIdx.x; i < NBUCK; i += 256) sH[i] = 0.f;
    for (int i = threadIdx.x; i < NCLASS * 5; i += 256) sS[i] = 0.f;
    __syncthreads();

    const int plane = blockIdx.x;
    const int c     = plane % 3;
    const float4* src = (const float4*)(x + plane * 4096);
    float* bhist = tail + T_BHIST + (unsigned)c * (NCLASS * NBUCK);

    float rCntL = 0.f, rSumL = 0.f, rCntR = 0.f, rSumR = 0.f, rSumIn = 0.f;

#pragma unroll
    for (int it = 0; it < 4; ++it) {
        int f4 = it * 256 + threadIdx.x;
        float4 val = src[f4];
        float vv[4] = {val.x, val.y, val.z, val.w};
        int pix0 = f4 * 4;
#pragma unroll
        for (int e = 0; e < 4; ++e) {
            int idx = pix0 + e;
            int py = idx >> 6, px = idx & 63;
            int rc = (py < 6) ? py : ((py >= 58) ? py - 51 : 6);
            int cc = (px < 6) ? px : ((px >= 58) ? px - 51 : 6);
            float v = vv[e];
            bool interior = (rc == 6) & (cc == 6);
            if (interior) {
                if (v < -0.25f)      { rCntL += 1.f; rSumL += v; }
                else if (v >= 0.25f) { rCntR += 1.f; rSumR += v; }
                else {
                    rSumIn += v;
                    int b = min(max((int)((v + 0.25f) * 1024.f), 0), NBUCK - 1);
                    atomicAdd(&sH[b], 1.f);
                }
            } else {
                int cl = rc * 13 + cc;
                if (v < -0.25f) {
                    atomicAdd(&sS[cl * 5 + 0], 1.f);
                    atomicAdd(&sS[cl * 5 + 1], v);
                } else if (v >= 0.25f) {
                    atomicAdd(&sS[cl * 5 + 2], 1.f);
                    atomicAdd(&sS[cl * 5 + 3], v);
                } else {
                    atomicAdd(&sS[cl * 5 + 4], v);
                    int b = min(max((int)((v + 0.25f) * 1024.f), 0), NBUCK - 1);
                    atomicAdd(&bhist[cl * NBUCK + b], 1.f);
                }
            }
        }
    }

    // wave-reduce the 5 interior register scalars
    const int lane = threadIdx.x & 63;
    const int wid  = threadIdx.x >> 6;
    float r5[5] = {rCntL, rSumL, rCntR, rSumR, rSumIn};
#pragma unroll
    for (int q = 0; q < 5; ++q) {
        float s = r5[q];
#pragma unroll
        for (int off = 32; off > 0; off >>= 1) s += __shfl_down(s, off);
        if (lane == 0) sred[wid][q] = s;
    }
    __syncthreads();

    if (threadIdx.x < 5) {
        float s = sred[0][threadIdx.x] + sred[1][threadIdx.x] +
                  sred[2][threadIdx.x] + sred[3][threadIdx.x];
        atomicAdd(&tail[T_SCAL + ((unsigned)c * NCLASS + CL_INT) * 5u + threadIdx.x], s);
    }
    // flush interior hist (spread addresses, 64 blocks/address)
    for (int b = threadIdx.x; b < NBUCK; b += 256) {
        float cn = sH[b];
        if (cn != 0.f)
            atomicAdd(&bhist[CL_INT * NBUCK + b], cn);
    }
    // flush boundary scalars
    for (int i = threadIdx.x; i < NCLASS * 5; i += 256) {
        int cl = i / 5;
        float s = sS[i];
        if (cl != CL_INT && s != 0.f)
            atomicAdd(&tail[T_SCAL + (unsigned)c * (NCLASS * 5) + i], s);
    }
}

// ---------------------------------------------------------------------------
// 2) tbuild: per (c,class) wave: T[j] = sum_b cnt_b * |center_j - center_b|
//    via double prefix scan:  T[j] = T0 + w*(2*Q[j] - j*N),  Q[j]=sum_{i<j}P[i].
// ---------------------------------------------------------------------------
__global__ __launch_bounds__(64) void tbuild_kernel(float* __restrict__ tail)
{
    __shared__ float P[NBUCK];
    const int id = blockIdx.x;                   // c*169+cl
    const float* hist = tail + T_BHIST + (unsigned)id * NBUCK;
    float* T = tail + T_TTAB + (unsigned)id * 513u;
    const int lane = threadIdx.x;

    float carry = 0.f, t0acc = 0.f;
#pragma unroll
    for (int ch = 0; ch < 8; ++ch) {
        int b = ch * 64 + lane;
        float cnt = hist[b];
        t0acc += (float)b * cnt;
        float ic = cnt;
#pragma unroll
        for (int off = 1; off < 64; off <<= 1) {
            float tc = __shfl_up(ic, off);
            if (lane >= off) ic += tc;
        }
        P[b] = carry + ic;
        carry += __shfl(ic, 63);
    }
    const float N = carry;                       // total in-range count
#pragma unroll
    for (int off = 32; off > 0; off >>= 1) t0acc += __shfl_down(t0acc, off);
    const float T0 = WB * __shfl(t0acc, 0);
    __syncthreads();

    float carryQ = 0.f;
#pragma unroll
    for (int ch = 0; ch < 8; ++ch) {
        int b = ch * 64 + lane;
        float pv = P[b];
        float ic = pv;
#pragma unroll
        for (int off = 1; off < 64; off <<= 1) {
            float tc = __shfl_up(ic, off);
            if (lane >= off) ic += tc;
        }
        float Q = carryQ + ic - pv;              // exclusive
        T[b] = T0 + WB * (2.f * Q - (float)b * N);
        carryQ += __shfl(ic, 63);
    }
    if (lane == 0) T[512] = T0 + WB * (2.f * carryQ - 512.f * N);
}

// ---------------------------------------------------------------------------
// 3) query: 4704 threads, one per (hm,o,c,dy,dx). Per valid class:
//    abs  += lerp(T,k) + (k*cntL - sumL) + (sumR - k*cntR)
//    lin  += k*Ntot_cl - (sumL + sumR + sumIn)
//    hit:  sum relu(k-v) = 0.5*(lin+abs);  miss: sum relu(v-k) = 0.5*(abs-lin)
// ---------------------------------------------------------------------------
__global__ __launch_bounds__(256) void query_kernel(
    const float* __restrict__ Kh, const float* __restrict__ Km,
    const float* __restrict__ tail, float* __restrict__ gsum)
{
    int tid = blockIdx.x * 256 + threadIdx.x;
    if (tid >= 4704) return;
    int hm = tid / 2352; int r = tid - hm * 2352;
    int o = r / 147;     int r2 = r - o * 147;
    int c = r2 / 49;     int t = r2 - c * 49;
    int dy = t / 7,      dx = t - dy * 7;
    float k = (hm ? Km : Kh)[(o * 3 + c) * 49 + t];
    float fb = (k + 0.25f) * 1024.f;
    int j = min(max((int)fb, 0), NBUCK - 1);
    float frac = fb - (float)j;

    float accA = 0.f, accL = 0.f;
    for (int i = 0; i < 7; ++i) {
        int rc = dy + i;
        float nr = (rc == 6) ? 52.f : 1.f;
        for (int jj = 0; jj < 7; ++jj) {
            int cc = dx + jj;
            float nc = (cc == 6) ? 52.f : 1.f;
            int id = c * NCLASS + rc * 13 + cc;
            const float* T  = tail + T_TTAB + (unsigned)id * 513u;
            const float* S5 = tail + T_SCAL + (unsigned)id * 5u;
            float t0 = T[j], t1 = T[j + 1];
            float A = t0 + frac * (t1 - t0);
            float cntL = S5[0], sumL = S5[1], cntR = S5[2], sumR = S5[3], sumIn = S5[4];
            accA += A + (k * cntL - sumL) + (sumR - k * cntR);
            accL += k * (nr * nc * 64.f) - (sumL + sumR + sumIn);
        }
    }
    if (hm == 0) atomicAdd(&gsum[o],      0.5f * (accL + accA));
    else         atomicAdd(&gsum[16 + o], 0.5f * (accA - accL));
}

// ---------------------------------------------------------------------------
// 4) fill: s_hit = -gsum[o], s_miss = gsum[16+o]; broadcast-fill 124 MB.
// ---------------------------------------------------------------------------
__global__ __launch_bounds__(256) void fill_kernel(
    const float* __restrict__ gsum, v4f* __restrict__ out, unsigned n4)
{
    __shared__ float sv[48];
    if (threadIdx.x < 48) {
        int o = threadIdx.x & 15, grp = threadIdx.x >> 4;
        float h = -gsum[o];
        float m = gsum[16 + o];
        sv[threadIdx.x] = (grp == 0) ? (h - m) : ((grp == 1) ? h : m);
    }
    __syncthreads();
    unsigned stride = gridDim.x * blockDim.x;
    for (unsigned i = blockIdx.x * blockDim.x + threadIdx.x; i < n4; i += stride) {
        unsigned f = i * 4u;
        unsigned w   = f / OUT1;
        unsigned rem = f - w * OUT1;
        unsigned o   = (rem % OSEG) / SEG;
        float val = sv[w * 16 + o];
        v4f pk = {val, val, val, val};
        __builtin_nontemporal_store(pk, &out[i]);
    }
}

extern "C" void kernel_launch(void* const* d_in, const int* in_sizes, int n_in,
                              void* d_out, int out_size, void* d_ws, size_t ws_size,
                              hipStream_t stream)
{
    const float* x  = (const float*)d_in[0];
    const float* Kh = (const float*)d_in[1];
    const float* Km = (const float*)d_in[2];
    float* out  = (float*)d_out;
    float* tail = out + TAIL_BASE;
    float* gsum = (float*)d_ws;        // 32 floats

    zero_kernel  <<<256, 256, 0, stream>>>(tail, gsum);
    build_kernel <<<192, 256, 0, stream>>>(x, tail);
    tbuild_kernel<<<507, 64, 0, stream>>>(tail);
    query_kernel <<<19, 256, 0, stream>>>(Kh, Km, tail, gsum);
    fill_kernel  <<<4096, 256, 0, stream>>>(gsum, (v4f*)out, NOUT / 4u);
}

// Round 9
// 73.582 us; speedup vs baseline: 1.4049x; 1.2580x over previous
//
#include <hip/hip_runtime.h>
#include <hip/hip_bf16.h>

// Problem constants: B=64, Cin=3, H=W=64, O=16, k=7, fh=fw=58
#define O_ 16
#define CIN 3
#define NBUCK 512
#define WB 0.0009765625f       // bucket width = 1/1024, range [-0.25, 0.25)
#define NCLASS 169             // 13 row-classes x 13 col-classes
#define CL_INT 84              // interior class (rc=6, cc=6)

// output geometry
#define SEG 10092u             // fh*fh*Cin
#define OSEG 161472u           // O*SEG
#define OUT1 10334208u         // B*OSEG
#define NOUT 31002624u         // 3*OUT1

// scratch in the TAIL of d_out (fill overwrites last). float offsets:
#define TAIL_BASE (NOUT - 786432u)      // 30,216,192
#define T_BHIST 0u                       // 3*169*512 = 259,584 count hist (ALL classes, atomics)
#define T_SCAL  259584u                  // 3*169*5 = 2,535 scalars (atomics)
#define T_TTAB  262144u                  // 3*169*513 T tables
#define ZERO_V4 65536u                   // zero [0, 262144) floats = hist + scalars

typedef float v4f __attribute__((ext_vector_type(4)));

// ---------------------------------------------------------------------------
// 0) zero: parallel zero of hist+scalar region + gsum banks.
// ---------------------------------------------------------------------------
__global__ __launch_bounds__(256) void zero_kernel(
    float* __restrict__ tail, float* __restrict__ gsum)
{
    v4f z = {0.f, 0.f, 0.f, 0.f};
    v4f* dst = (v4f*)tail;
    unsigned stride = gridDim.x * blockDim.x;
    for (unsigned i = blockIdx.x * blockDim.x + threadIdx.x; i < ZERO_V4; i += stride)
        dst[i] = z;
    if (blockIdx.x == 0 && threadIdx.x < 64) gsum[threadIdx.x] = 0.f;
}

// ---------------------------------------------------------------------------
// 1) build: one block per (b,c) plane (unchanged from R8).
//    Interior scalars in registers -> shuffle reduce -> 5 global atomics.
//    Interior in-range hist in LDS (spread) -> spread global atomic flush.
//    Boundary classes: LDS atomics -> global atomic flush.
// ---------------------------------------------------------------------------
__global__ __launch_bounds__(256) void build_kernel(
    const float* __restrict__ x, float* __restrict__ tail)
{
    __shared__ float sH[NBUCK];          // interior in-range count hist
    __shared__ float sS[NCLASS * 5];     // boundary-class scalars (CL_INT slots unused)
    __shared__ float sred[4][5];
    for (int i = threadIdx.x; i < NBUCK; i += 256) sH[i] = 0.f;
    for (int i = threadIdx.x; i < NCLASS * 5; i += 256) sS[i] = 0.f;
    __syncthreads();

    const int plane = blockIdx.x;
    const int c     = plane % 3;
    const float4* src = (const float4*)(x + plane * 4096);
    float* bhist = tail + T_BHIST + (unsigned)c * (NCLASS * NBUCK);

    float rCntL = 0.f, rSumL = 0.f, rCntR = 0.f, rSumR = 0.f, rSumIn = 0.f;

#pragma unroll
    for (int it = 0; it < 4; ++it) {
        int f4 = it * 256 + threadIdx.x;
        float4 val = src[f4];
        float vv[4] = {val.x, val.y, val.z, val.w};
        int pix0 = f4 * 4;
#pragma unroll
        for (int e = 0; e < 4; ++e) {
            int idx = pix0 + e;
            int py = idx >> 6, px = idx & 63;
            int rc = (py < 6) ? py : ((py >= 58) ? py - 51 : 6);
            int cc = (px < 6) ? px : ((px >= 58) ? px - 51 : 6);
            float v = vv[e];
            bool interior = (rc == 6) & (cc == 6);
            if (interior) {
                if (v < -0.25f)      { rCntL += 1.f; rSumL += v; }
                else if (v >= 0.25f) { rCntR += 1.f; rSumR += v; }
                else {
                    rSumIn += v;
                    int b = min(max((int)((v + 0.25f) * 1024.f), 0), NBUCK - 1);
                    atomicAdd(&sH[b], 1.f);
                }
            } else {
                int cl = rc * 13 + cc;
                if (v < -0.25f) {
                    atomicAdd(&sS[cl * 5 + 0], 1.f);
                    atomicAdd(&sS[cl * 5 + 1], v);
                } else if (v >= 0.25f) {
                    atomicAdd(&sS[cl * 5 + 2], 1.f);
                    atomicAdd(&sS[cl * 5 + 3], v);
                } else {
                    atomicAdd(&sS[cl * 5 + 4], v);
                    int b = min(max((int)((v + 0.25f) * 1024.f), 0), NBUCK - 1);
                    atomicAdd(&bhist[cl * NBUCK + b], 1.f);
                }
            }
        }
    }

    const int lane = threadIdx.x & 63;
    const int wid  = threadIdx.x >> 6;
    float r5[5] = {rCntL, rSumL, rCntR, rSumR, rSumIn};
#pragma unroll
    for (int q = 0; q < 5; ++q) {
        float s = r5[q];
#pragma unroll
        for (int off = 32; off > 0; off >>= 1) s += __shfl_down(s, off);
        if (lane == 0) sred[wid][q] = s;
    }
    __syncthreads();

    if (threadIdx.x < 5) {
        float s = sred[0][threadIdx.x] + sred[1][threadIdx.x] +
                  sred[2][threadIdx.x] + sred[3][threadIdx.x];
        atomicAdd(&tail[T_SCAL + ((unsigned)c * NCLASS + CL_INT) * 5u + threadIdx.x], s);
    }
    for (int b = threadIdx.x; b < NBUCK; b += 256) {
        float cn = sH[b];
        if (cn != 0.f)
            atomicAdd(&bhist[CL_INT * NBUCK + b], cn);
    }
    for (int i = threadIdx.x; i < NCLASS * 5; i += 256) {
        int cl = i / 5;
        float s = sS[i];
        if (cl != CL_INT && s != 0.f)
            atomicAdd(&tail[T_SCAL + (unsigned)c * (NCLASS * 5) + i], s);
    }
}

// ---------------------------------------------------------------------------
// 2) tbuild: per (c,class) wave: T[j] = sum_b cnt_b * |center_j - center_b|
//    via double prefix scan (unchanged from R8).
// ---------------------------------------------------------------------------
__global__ __launch_bounds__(64) void tbuild_kernel(float* __restrict__ tail)
{
    __shared__ float P[NBUCK];
    const int id = blockIdx.x;                   // c*169+cl
    const float* hist = tail + T_BHIST + (unsigned)id * NBUCK;
    float* T = tail + T_TTAB + (unsigned)id * 513u;
    const int lane = threadIdx.x;

    float carry = 0.f, t0acc = 0.f;
#pragma unroll
    for (int ch = 0; ch < 8; ++ch) {
        int b = ch * 64 + lane;
        float cnt = hist[b];
        t0acc += (float)b * cnt;
        float ic = cnt;
#pragma unroll
        for (int off = 1; off < 64; off <<= 1) {
            float tc = __shfl_up(ic, off);
            if (lane >= off) ic += tc;
        }
        P[b] = carry + ic;
        carry += __shfl(ic, 63);
    }
    const float N = carry;
#pragma unroll
    for (int off = 32; off > 0; off >>= 1) t0acc += __shfl_down(t0acc, off);
    const float T0 = WB * __shfl(t0acc, 0);
    __syncthreads();

    float carryQ = 0.f;
#pragma unroll
    for (int ch = 0; ch < 8; ++ch) {
        int b = ch * 64 + lane;
        float pv = P[b];
        float ic = pv;
#pragma unroll
        for (int off = 1; off < 64; off <<= 1) {
            float tc = __shfl_up(ic, off);
            if (lane >= off) ic += tc;
        }
        float Q = carryQ + ic - pv;
        T[b] = T0 + WB * (2.f * Q - (float)b * N);
        carryQ += __shfl(ic, 63);
    }
    if (lane == 0) T[512] = T0 + WB * (2.f * carryQ - 512.f * N);
}

// ---------------------------------------------------------------------------
// 3) query: RESTRUCTURED. Block per (channel, 16-class chunk) = 33 blocks.
//    Tables staged coalesced into LDS; the data-dependent scattered reads
//    hit LDS (cheap) instead of 64-line-scattered global loads (the ~50us
//    monster in R8: 74 waves x 2.4K scattered wave-loads x ~64 TA-cyc).
//    Thread = (hm,o,tslot); iterate (class, tap) with validity check.
//    gsum banks: [0..32) accA (hm*16+o), [32..64) accL.
// ---------------------------------------------------------------------------
#define QCHUNK 16
#define NCHUNK 11              // ceil(169/16)

__global__ __launch_bounds__(256) void query_kernel(
    const float* __restrict__ Kh, const float* __restrict__ Km,
    const float* __restrict__ tail, float* __restrict__ gsum)
{
    __shared__ float sT[QCHUNK][513];       // 32.8 KB (odd stride -> bank-friendly)
    __shared__ float sS5[QCHUNK][5];
    __shared__ float sK[2][16][49];
    __shared__ float sredA[32][8];
    __shared__ float sredL[32][8];

    const int c     = blockIdx.x / NCHUNK;
    const int chunk = blockIdx.x % NCHUNK;
    const int cl0   = chunk * QCHUNK;
    const int ncl   = min(QCHUNK, NCLASS - cl0);

    for (int i = threadIdx.x; i < ncl * 513; i += 256) {
        int l = i / 513, j = i - l * 513;
        sT[l][j] = tail[T_TTAB + (unsigned)(c * NCLASS + cl0 + l) * 513u + j];
    }
    for (int i = threadIdx.x; i < ncl * 5; i += 256) {
        int l = i / 5, q = i - l * 5;
        sS5[l][q] = tail[T_SCAL + (unsigned)(c * NCLASS + cl0 + l) * 5u + q];
    }
    for (int i = threadIdx.x; i < 2 * 16 * 49; i += 256) {
        int hm = i / 784, r = i - hm * 784, o = r / 49, t = r - o * 49;
        sK[hm][o][t] = (hm ? Km : Kh)[o * 147 + c * 49 + t];
    }
    __syncthreads();

    const int hm = threadIdx.x >> 7;
    const int o  = (threadIdx.x >> 3) & 15;
    const int ts = threadIdx.x & 7;

    float accA = 0.f, accL = 0.f;
    for (int l = 0; l < ncl; ++l) {
        int cl = cl0 + l;
        int rc = cl / 13, cc = cl - rc * 13;
        int dyl = max(0, rc - 6), dyh = min(6, rc);
        int dxl = max(0, cc - 6), dxh = min(6, cc);
        float nr  = (rc == 6) ? 52.f : 1.f;
        float nc_ = (cc == 6) ? 52.f : 1.f;
        float Ncl = nr * nc_ * 64.f;
        float cntL = sS5[l][0], sumL = sS5[l][1];
        float cntR = sS5[l][2], sumR = sS5[l][3], sumIn = sS5[l][4];
        float sAll = sumL + sumR + sumIn;
        for (int t = ts; t < 49; t += 8) {
            int dy = t / 7, dx = t - dy * 7;
            if (dy >= dyl && dy <= dyh && dx >= dxl && dx <= dxh) {
                float k = sK[hm][o][t];
                float fb = (k + 0.25f) * 1024.f;
                int j = min(max((int)fb, 0), NBUCK - 1);
                float frac = fb - (float)j;
                float t0 = sT[l][j], t1 = sT[l][j + 1];
                accA += t0 + frac * (t1 - t0) + k * (cntL - cntR) - sumL + sumR;
                accL += k * Ncl - sAll;
            }
        }
    }
    sredA[hm * 16 + o][ts] = accA;
    sredL[hm * 16 + o][ts] = accL;
    __syncthreads();
    if (threadIdx.x < 64) {
        int idx  = threadIdx.x >> 1;     // 0..31 = hm*16+o
        int part = threadIdx.x & 1;      // 0=A, 1=L
        const float (*sr)[8] = part ? sredL : sredA;
        float s = 0.f;
#pragma unroll
        for (int q = 0; q < 8; ++q) s += sr[idx][q];
        atomicAdd(&gsum[part * 32 + idx], s);
    }
}

// ---------------------------------------------------------------------------
// 4) fill: fold A/L banks -> s_hit/s_miss; broadcast-fill 124 MB.
//    s_hit  = -0.5*(accL_hit + accA_hit);  s_miss = 0.5*(accA_miss - accL_miss)
// ---------------------------------------------------------------------------
__global__ __launch_bounds__(256) void fill_kernel(
    const float* __restrict__ gsum, v4f* __restrict__ out, unsigned n4)
{
    __shared__ float sv[48];
    if (threadIdx.x < 48) {
        int o = threadIdx.x & 15, grp = threadIdx.x >> 4;
        float h = -0.5f * (gsum[32 + o] + gsum[o]);
        float m =  0.5f * (gsum[16 + o] - gsum[48 + o]);
        sv[threadIdx.x] = (grp == 0) ? (h - m) : ((grp == 1) ? h : m);
    }
    __syncthreads();
    unsigned stride = gridDim.x * blockDim.x;
    for (unsigned i = blockIdx.x * blockDim.x + threadIdx.x; i < n4; i += stride) {
        unsigned f = i * 4u;
        unsigned w   = f / OUT1;
        unsigned rem = f - w * OUT1;
        unsigned o   = (rem % OSEG) / SEG;
        float val = sv[w * 16 + o];
        v4f pk = {val, val, val, val};
        __builtin_nontemporal_store(pk, &out[i]);
    }
}

extern "C" void kernel_launch(void* const* d_in, const int* in_sizes, int n_in,
                              void* d_out, int out_size, void* d_ws, size_t ws_size,
                              hipStream_t stream)
{
    const float* x  = (const float*)d_in[0];
    const float* Kh = (const float*)d_in[1];
    const float* Km = (const float*)d_in[2];
    float* out  = (float*)d_out;
    float* tail = out + TAIL_BASE;
    float* gsum = (float*)d_ws;        // 64 floats: [0..32) A-bank, [32..64) L-bank

    zero_kernel  <<<256, 256, 0, stream>>>(tail, gsum);
    build_kernel <<<192, 256, 0, stream>>>(x, tail);
    tbuild_kernel<<<507, 64, 0, stream>>>(tail);
    query_kernel <<<3 * NCHUNK, 256, 0, stream>>>(Kh, Km, tail, gsum);
    fill_kernel  <<<4096, 256, 0, stream>>>(gsum, (v4f*)out, NOUT / 4u);
}